// Round 24
// baseline (209.765 us; speedup 1.0000x reference)
//
#include <hip/hip_runtime.h>
#include <math.h>

#define T_TOK 16384
#define M_MSG 256
#define L_TOK 64
#define KK 6
#define NQ (M_MSG * KK)   // 1536
#define D_HID 256
#define NH 4
#define HD 64
#define KT 10
#define NBATCH 8

// ---------- helpers ----------
__device__ __forceinline__ unsigned ordf(float f) {
  unsigned u = __float_as_uint(f);
  return (u & 0x80000000u) ? ~u : (u | 0x80000000u);
}
__device__ __forceinline__ float unordf(unsigned u) {
  return __uint_as_float((u & 0x80000000u) ? (u ^ 0x80000000u) : ~u);
}

typedef _Float16 h2v __attribute__((ext_vector_type(2)));
typedef _Float16 h8v __attribute__((ext_vector_type(8)));
typedef float f4v __attribute__((ext_vector_type(4)));
typedef __fp16 fp16x2 __attribute__((ext_vector_type(2)));  // cvt_pkrtz ret type
__device__ __forceinline__ h2v u2h(unsigned u) {
  return __builtin_bit_cast(h2v, u);
}
// pack two f32 -> f16x2 (RTZ; v_cvt_pkrtz_f16_f32, available all gfx9+)
__device__ __forceinline__ unsigned pkh(float a, float b) {
  fp16x2 h = __builtin_amdgcn_cvt_pkrtz(a, b);
  return __builtin_bit_cast(unsigned, h);
}
#if defined(__has_builtin) && __has_builtin(__builtin_amdgcn_fdot2)
__device__ __forceinline__ float FDOT2(h2v a, h2v b, float c) {
  return __builtin_amdgcn_fdot2(a, b, c, false);  // v_dot2_f32_f16: 2 MACs
}
#else
__device__ __forceinline__ float FDOT2(h2v a, h2v b, float c) {
  return c + (float)a.x * (float)b.x + (float)a.y * (float)b.y;
}
#endif

// ---------- 0. weight panel transpose ----------
// WqP/WoP/Wi1P: f32 k-panels (coalesced float4 per column).
// WkH/WvH: f16-packed dim-major panels WH[d8*256+c] = uint4 of dims
// d8*8..d8*8+7 of column c (= the MFMA B-fragment layout).
__global__ __launch_bounds__(64) void wpanel_kernel(
    const float* __restrict__ Wk, const float* __restrict__ Wv,
    const float* __restrict__ Wq, const float* __restrict__ Wo,
    const float* __restrict__ Wi1, uint4* __restrict__ WkH,
    uint4* __restrict__ WvH, float4* __restrict__ WqP,
    float4* __restrict__ WoP, float4* __restrict__ Wi1P) {
  int c = blockIdx.x;    // 0..255 (column)
  int t = threadIdx.x;   // 0..63
  WqP[t * 256 + c] = ((const float4*)(Wq + (size_t)c * 256))[t];
  WoP[t * 256 + c] = ((const float4*)(Wo + (size_t)c * 256))[t];
  if (c < 128) Wi1P[t * 128 + c] = ((const float4*)(Wi1 + (size_t)c * 256))[t];
  const float* Wsrc = (t < 32) ? Wk : Wv;
  uint4* dst = (t < 32) ? WkH : WvH;
  int d8 = t & 31;
  float4 a = ((const float4*)(Wsrc + (size_t)c * 256))[d8 * 2];
  float4 b = ((const float4*)(Wsrc + (size_t)c * 256))[d8 * 2 + 1];
  uint4 p;
  p.x = pkh(a.x, a.y);
  p.y = pkh(a.z, a.w);
  p.z = pkh(b.x, b.y);
  p.w = pkh(b.z, b.w);
  dst[d8 * 256 + c] = p;
}

// ---------- 1. fused KV-projection (MFMA f16) + importance MLP (f32) ----------
__global__ __launch_bounds__(256) void kvimp_kernel(
    const float* __restrict__ X, const uint4* __restrict__ WkH,
    const float* __restrict__ bk, const uint4* __restrict__ WvH,
    const float* __restrict__ bv, const float4* __restrict__ Wi1P,
    const float* __restrict__ bi1, const float* __restrict__ Wi2,
    const float* __restrict__ bi2, unsigned* __restrict__ Kout,
    float* __restrict__ Vout, float* __restrict__ imp) {
  __shared__ float xs[32][260];  // rows 0..8: f16 X tile; rows 16..31: K res
  __shared__ float partial[4][16];
  int tid = threadIdx.x;
  if (blockIdx.x < 1024) {
    // ---- KV path (16 rows, MFMA) ----
    int r0 = blockIdx.x * 16;
    unsigned* xh = (unsigned*)&xs[0][0];  // [16][132] u32 (row = 528 B)
    const float4* Xv = (const float4*)(X + (size_t)r0 * 256);
#pragma unroll
    for (int i = 0; i < 2; ++i) {
      int n = i * 256 + tid;   // 0..511
      int row = n >> 5, d8 = n & 31;
      float4 a = Xv[row * 64 + d8 * 2];
      float4 b = Xv[row * 64 + d8 * 2 + 1];
      uint4 p;
      p.x = pkh(a.x, a.y);
      p.y = pkh(a.z, a.w);
      p.z = pkh(b.x, b.y);
      p.w = pkh(b.z, b.w);
      ((uint4*)(xh + row * 132))[d8] = p;
    }
    __syncthreads();
    int lane = tid & 63, w = tid >> 6;
    int mat = w >> 1;            // 0 = K, 1 = V
    int cbase = (w & 1) * 128;   // column base for this wave
    int arow = lane & 15, akg = lane >> 4;
    const uint4* P = mat ? WvH : WkH;
    // hoist A-fragments (shared across the wave's 8 col-tiles)
    uint4 a8[8];
#pragma unroll
    for (int kb = 0; kb < 8; ++kb)
      a8[kb] = ((const uint4*)xh)[arow * 33 + kb * 4 + akg];
#pragma unroll
    for (int tt = 0; tt < 8; ++tt) {
      int c0 = cbase + tt * 16;
      f4v acc = {0.f, 0.f, 0.f, 0.f};
#pragma unroll
      for (int kb = 0; kb < 8; ++kb) {
        uint4 b = P[(size_t)(kb * 4 + akg) * 256 + c0 + arow];
        acc = __builtin_amdgcn_mfma_f32_16x16x32_f16(
            __builtin_bit_cast(h8v, a8[kb]), __builtin_bit_cast(h8v, b), acc,
            0, 0, 0);
      }
      int col = c0 + arow;
      if (mat == 0) {
        float bb = bk[col];
#pragma unroll
        for (int r = 0; r < 4; ++r)
          xs[16 + akg * 4 + r][col] = acc[r] + bb;
      } else {
        float bb = bv[col];
#pragma unroll
        for (int r = 0; r < 4; ++r)
          Vout[(size_t)(r0 + akg * 4 + r) * 256 + col] = acc[r] + bb;
      }
    }
    __syncthreads();  // K results visible in rows 16..31
    uint4* Kbv = (uint4*)Kout;
#pragma unroll
    for (int i = 0; i < 2; ++i) {
      int idx = i * 256 + tid;    // 0..511
      int hd8 = idx >> 4;         // 0..31 (h*8 + d8)
      int r = idx & 15;
      const float* row = &xs[16 + r][hd8 * 8];
      uint4 p;
      p.x = pkh(row[0], row[1]);
      p.y = pkh(row[2], row[3]);
      p.z = pkh(row[4], row[5]);
      p.w = pkh(row[6], row[7]);
      Kbv[(size_t)hd8 * T_TOK + r0 + r] = p;
    }
  } else {
    // ---- imp path (32 tokens; grp g = tid>>7 owns tokens g*16..+15) ----
    int t0 = (blockIdx.x - 1024) * 32;
    const float4* Xv = (const float4*)(X + (size_t)t0 * 256);
    for (int n = tid; n < 2048; n += 256) {
      int row = n >> 6, sl = n & 63;
      ((float4*)xs[row])[sl] = Xv[row * 64 + sl];
    }
    __syncthreads();
    int j = tid & 127, grp = tid >> 7;
    float acc[16];
#pragma unroll
    for (int tt = 0; tt < 16; ++tt) acc[tt] = 0.f;
    for (int i4 = 0; i4 < 64; ++i4) {
      float4 w = Wi1P[i4 * 128 + j];
#pragma unroll
      for (int tt = 0; tt < 16; ++tt) {
        float4 x = ((const float4*)xs[grp * 16 + tt])[i4];
        acc[tt] += x.x * w.x + x.y * w.y + x.z * w.z + x.w * w.w;
      }
    }
    float b1 = bi1[j], w2 = Wi2[j];
    float p[16];
#pragma unroll
    for (int tt = 0; tt < 16; ++tt) {
      float hh = acc[tt] + b1;
      hh = hh > 0.f ? hh : 0.f;
      p[tt] = hh * w2;
    }
#pragma unroll
    for (int s = 1; s < 64; s <<= 1) {
#pragma unroll
      for (int tt = 0; tt < 16; ++tt) p[tt] += __shfl_xor(p[tt], s, 64);
    }
    int lane = tid & 63, wv_ = tid >> 6;
    if (lane == 0) {
#pragma unroll
      for (int tt = 0; tt < 16; ++tt) partial[wv_][tt] = p[tt];
    }
    __syncthreads();
    if (tid < 32) {
      int g = tid >> 4, tt = tid & 15;
      imp[t0 + g * 16 + tt] =
          partial[2 * g][tt] + partial[2 * g + 1][tt] + bi2[0];
    }
  }
}

// ---------- 2. top-6 select + Q projection (fused) + (block M_MSG) ranges ----------
__global__ __launch_bounds__(256) void topselq_kernel(
    const float* __restrict__ imp, const int* __restrict__ mb,
    const int* __restrict__ bidx, const float* __restrict__ X,
    const float4* __restrict__ WqP, const float* __restrict__ bq,
    int* __restrict__ selected, int* __restrict__ lo, int* __restrict__ hi,
    float* __restrict__ Qout) {
  int m = blockIdx.x;
  int tid = threadIdx.x;
  if (m == M_MSG) {  // fused ranges computation
    int g = tid;
    if (g < NBATCH) {
      int l = 0;
      while (l < M_MSG && bidx[l] < g) ++l;
      int h = l;
      while (h < M_MSG && bidx[h] == g) ++h;
      lo[g] = l * L_TOK;
      hi[g] = h * L_TOK;
    }
    return;
  }
  __shared__ int sel[KK];
  __shared__ float4 xs6[KK][64];  // 6 selected rows x 256 floats (full row)
  if (tid < 64) {  // wave 0: top-6 selection
    int l = tid;
    float myv = imp[m * 64 + l];
    int start = mb[2 * m];
    for (int k = 0; k < KK; ++k) {
      float rv = myv;
      int ri = l;
#pragma unroll
      for (int s = 1; s < 64; s <<= 1) {
        float ov = __shfl_xor(rv, s, 64);
        int oi = __shfl_xor(ri, s, 64);
        if (ov > rv || (ov == rv && oi < ri)) { rv = ov; ri = oi; }
      }
      if (l == 0) {
        selected[m * KK + k] = start + ri;
        sel[k] = start + ri;
      }
      if (l == ri) myv = -INFINITY;
    }
  }
  __syncthreads();
  for (int i = tid; i < KK * 64; i += 256) {  // stage full selected rows
    int r = i >> 6, d4 = i & 63;
    xs6[r][d4] = ((const float4*)X)[(size_t)sel[r] * 64 + d4];
  }
  __syncthreads();
  float acc[KK];
#pragma unroll
  for (int r = 0; r < KK; ++r) acc[r] = 0.f;
  for (int i4 = 0; i4 < 64; ++i4) {
    float4 w = WqP[i4 * 256 + tid];
#pragma unroll
    for (int r = 0; r < KK; ++r) {
      float4 x = xs6[r][i4];
      acc[r] += x.x * w.x + x.y * w.y + x.z * w.z + x.w * w.w;
    }
  }
  float bj = bq[tid];
#pragma unroll
  for (int r = 0; r < KK; ++r)
    Qout[(size_t)(m * KK + r) * 256 + tid] = (acc[r] + bj) * 0.125f;
}

// ---------- 5. scores via MFMA + per-(split,wave) top-10 ----------
// block = (m, h, split): 2048 blocks, 128 threads = 2 waves; the 2 waves
// SUB-SPLIT the split's chunks (halves total K-load instrs, the measured
// binding resource: 0.52M -> 0.26M) because one MFMA wave computes ALL 6
// queries. Per 64-key chunk: 4 key-tiles x 2 kb = 8 A-loads + 8
// v_mfma_f32_16x16x32_f16 (A = K-tile: lane holds key row lane&15, dims
// (lane>>4)*8; B = Q: col lane&15 = query, 2 hoisted frags). C/D mapping
// (hardware-verified by r22 kvimp): col=lane&15 (query), row=grp*4+reg
// (key in tile). Lane owns ONE query -> single u64 top-10 list (20 VGPR).
// Final merge across the 4 lanes sharing lane&15 via shfl_xor(16/32).
// 4 lists per (q,h) merged exactly in finish (r20-validated 4-way).
__global__ __launch_bounds__(128) void scores_kernel(
    const float* __restrict__ Q, const unsigned* __restrict__ Kb,
    const int* __restrict__ lo_, const int* __restrict__ hi_,
    const int* __restrict__ bidx, unsigned long long* __restrict__ topk2) {
  int bid = blockIdx.x;
  // XCD swizzle: contiguous 256-block slab per XCD (bidx sorted).
  int sw = (bid & 7) * (M_MSG * NH * 2 / 8) + (bid >> 3);
  int m = sw >> 3;
  int h = (sw >> 1) & 3;
  int sp = sw & 1;
  int tid = threadIdx.x, lane = tid & 63, w = tid >> 6;
  int g = bidx[m];
  int lo = lo_[g], hi = hi_[g];
  int range = hi - lo;
  int n_all = (range + 63) >> 6;
  int n0 = (n_all + 1) >> 1;
  int nt_sp = sp ? (n_all - n0) : n0;
  int start_sp = lo + (sp ? n0 * 64 : 0);
  // sub-split this split's chunks across the block's 2 waves
  int ntw0 = (nt_sp + 1) >> 1;
  int nt = w ? (nt_sp - ntw0) : ntw0;
  int start = start_sp + (w ? ntw0 * 64 : 0);

  __shared__ uint4 qh[KK][8];  // 6 queries x 64 dims f16-packed (768 B)
  const float4* Qv = (const float4*)Q;
  for (int i = tid; i < KK * 8; i += 128) {
    int qq = i >> 3, d8 = i & 7;
    float4 a = Qv[(size_t)(m * KK + qq) * 64 + h * 16 + d8 * 2];
    float4 b = Qv[(size_t)(m * KK + qq) * 64 + h * 16 + d8 * 2 + 1];
    uint4 p;
    p.x = pkh(a.x, a.y);
    p.y = pkh(a.z, a.w);
    p.z = pkh(b.x, b.y);
    p.w = pkh(b.z, b.w);
    qh[qq][d8] = p;
  }
  __syncthreads();

  int qcol = lane & 15;         // this lane's query (cols 6..15 unused)
  int grp = lane >> 4;          // 0..3
  int qcl = qcol < KK ? qcol : KK - 1;
  uint4 bf0 = qh[qcl][grp];     // B-frag kb=0 (dims grp*8)
  uint4 bf1 = qh[qcl][4 + grp]; // B-frag kb=1 (dims 32+grp*8)
  bool qvalid = qcol < KK;

  unsigned long long lst[KT];
#pragma unroll
  for (int k = 0; k < KT; ++k) lst[k] = 0ULL;

  const uint4* Kh = (const uint4*)Kb + (size_t)h * 8 * T_TOK;

#pragma unroll 1
  for (int kb = 0; kb < nt; ++kb) {
    int tb = start + kb * 64;
#pragma unroll
    for (int tt = 0; tt < 4; ++tt) {
      int ta = tb + tt * 16 + qcol;           // A-row key (lane&15)
      int tca = ta < hi ? ta : hi - 1;
      uint4 a0 = Kh[(size_t)(0 * 4 + grp) * T_TOK + tca];
      uint4 a1 = Kh[(size_t)(1 * 4 + grp) * T_TOK + tca];
      f4v acc = {0.f, 0.f, 0.f, 0.f};
      acc = __builtin_amdgcn_mfma_f32_16x16x32_f16(
          __builtin_bit_cast(h8v, a0), __builtin_bit_cast(h8v, bf0), acc,
          0, 0, 0);
      acc = __builtin_amdgcn_mfma_f32_16x16x32_f16(
          __builtin_bit_cast(h8v, a1), __builtin_bit_cast(h8v, bf1), acc,
          0, 0, 0);
      // lane holds scores: query=qcol, keys tb+tt*16+grp*4+{0..3}
      int k0 = tb + tt * 16 + grp * 4;
#pragma unroll
      for (int r = 0; r < 4; ++r) {
        int t = k0 + r;
        bool v0 = qvalid && (t < hi) && ((t >> 6) != m);
        unsigned cc = v0 ? ordf(acc[r]) : 0u;
        unsigned long long key =
            cc ? (((unsigned long long)cc << 32) | (unsigned)(~t)) : 0ULL;
        if (key > lst[KT - 1]) {
          unsigned long long ins = key;
#pragma unroll
          for (int rr = 0; rr < KT; ++rr) {
            unsigned long long cur = lst[rr];
            unsigned long long mx = ins > cur ? ins : cur;
            unsigned long long mn = ins > cur ? cur : ins;
            lst[rr] = mx;
            ins = mn;
          }
        }
      }
    }
  }

  // ---- extraction merge across the 4 lanes sharing qcol (xor 16,32) ----
  for (int k = 0; k < KT; ++k) {
    unsigned long long mx = lst[0];
    unsigned long long o = __shfl_xor(mx, 16, 64);
    if (o > mx) mx = o;
    o = __shfl_xor(mx, 32, 64);
    if (o > mx) mx = o;
    if (mx != 0ULL && lst[0] == mx) {  // unique owner pops
#pragma unroll
      for (int r = 0; r < KT - 1; ++r) lst[r] = lst[r + 1];
      lst[KT - 1] = 0ULL;
    }
    if (lane < KK) {  // lanes 0..5: grp==0, qcol==lane
      int q = m * KK + lane;
      topk2[((size_t)(q * NH + h) * 4 + sp * 2 + w) * KT + k] = mx;
    }
  }
}

// ---------- 6. 4-way merge + softmax + gather V + Wo + scatter-add + avg ----------
// 4 queries/block (384 blocks, r23 grid) with the r20-validated branchless
// 4-pointer exact merge (nonzero u64 keys unique across the 4 lists;
// at round k each pointer <= k <= 9 -> in-bounds).
__global__ __launch_bounds__(256) void finish_kernel(
    const unsigned long long* __restrict__ topk2, const float* __restrict__ V,
    const float4* __restrict__ WoP, const float* __restrict__ bo,
    const int* __restrict__ selected, float* __restrict__ out,
    float* __restrict__ out_avg) {
  int q0 = blockIdx.x * 4;
  int tid = threadIdx.x;
  __shared__ unsigned long long buf[16][4 * KT];  // 5 KB
  __shared__ float tvs[4][NH][KT];
  __shared__ int tis[4][NH][KT];
  __shared__ float wsm[4][NH * KT];
  __shared__ float att[4][256];
  // stage the 16 (q,h) pairs' 4 split lists
  const unsigned long long* src = topk2 + (size_t)q0 * NH * 4 * KT;
  for (int i = tid; i < 16 * 4 * KT; i += 256) (&buf[0][0])[i] = src[i];
  __syncthreads();
  if (tid < 16) {
    int qq = tid >> 2, h = tid & 3;
    int pa = 0, pb = 0, pc = 0, pd = 0;
    float e[KT];
    float m0 = 0.f, sum = 0.f;
#pragma unroll
    for (int k = 0; k < KT; ++k) {
      unsigned long long va = buf[tid][pa];
      unsigned long long vb = buf[tid][KT + pb];
      unsigned long long vc = buf[tid][2 * KT + pc];
      unsigned long long vd = buf[tid][3 * KT + pd];
      unsigned long long m1 = va >= vb ? va : vb;
      unsigned long long m2 = vc >= vd ? vc : vd;
      unsigned long long v = m1 >= m2 ? m1 : m2;
      if (v == va) ++pa;
      else if (v == vb) ++pb;
      else if (v == vc) ++pc;
      else ++pd;
      float scv;
      int t;
      if (v != 0ULL) {
        scv = unordf((unsigned)(v >> 32));
        t = (int)(~(unsigned)v);
      } else {
        scv = -1e30f;
        t = 0;
      }
      tvs[qq][h][k] = scv;
      tis[qq][h][k] = t;
      if (k == 0) m0 = scv;
      e[k] = expf(scv - m0);
      sum += e[k];
    }
    float inv = 1.f / sum;
#pragma unroll
    for (int k = 0; k < KT; ++k) wsm[qq][h * KT + k] = e[k] * inv;
  }
  __syncthreads();
  if (tid < 40) {
    int qq = tid / 10, k = tid % 10;
    out_avg[(size_t)(q0 + qq) * KT + k] =
        0.25f * (tvs[qq][0][k] + tvs[qq][1][k] + tvs[qq][2][k] + tvs[qq][3][k]);
  }
  int h = tid >> 6, d = tid & 63;
#pragma unroll 1
  for (int qq = 0; qq < 4; ++qq) {
    float a = 0.f;
#pragma unroll
    for (int k = 0; k < KT; ++k) {
      int t = tis[qq][h][k];
      a += wsm[qq][h * KT + k] * V[(size_t)t * 256 + h * 64 + d];
    }
    att[qq][tid] = a;
  }
  __syncthreads();
  float acc[4];
#pragma unroll
  for (int tt = 0; tt < 4; ++tt) acc[tt] = 0.f;
  for (int i4 = 0; i4 < 64; ++i4) {
    float4 wv = WoP[i4 * 256 + tid];  // coalesced panel load (L2-resident)
#pragma unroll
    for (int tt = 0; tt < 4; ++tt) {
      float4 x = ((const float4*)att[tt])[i4];
      acc[tt] += x.x * wv.x + x.y * wv.y + x.z * wv.z + x.w * wv.w;
    }
  }
  float bj = bo[tid];
#pragma unroll 1
  for (int tt = 0; tt < 4; ++tt) {
    int s = selected[q0 + tt];
    out[(size_t)s * 256 + tid] += acc[tt] + bj;
  }
}

// ---------- launch ----------
extern "C" void kernel_launch(void* const* d_in, const int* in_sizes, int n_in,
                              void* d_out, int out_size, void* d_ws, size_t ws_size,
                              hipStream_t stream) {
  const float* X   = (const float*)d_in[0];
  const int*   mb  = (const int*)d_in[1];
  const int*   bidx= (const int*)d_in[2];
  const float* Wq  = (const float*)d_in[3];
  const float* bq  = (const float*)d_in[4];
  const float* Wk  = (const float*)d_in[5];
  const float* bk  = (const float*)d_in[6];
  const float* Wv  = (const float*)d_in[7];
  const float* bv  = (const float*)d_in[8];
  const float* Wi1 = (const float*)d_in[9];
  const float* bi1 = (const float*)d_in[10];
  const float* Wi2 = (const float*)d_in[11];
  const float* bi2 = (const float*)d_in[12];
  const float* Wo  = (const float*)d_in[13];
  const float* bo  = (const float*)d_in[14];

  float* out = (float*)d_out;
  float* out_avg = out + (size_t)T_TOK * D_HID;

  // K (f16 packed, 8 MB) is staged in d_out's "updated" region
  // (dead until final memcpy+scatter).
  unsigned* Kmat = (unsigned*)out;

  char* ws = (char*)d_ws;
  size_t off = 0;
  float* V = (float*)(ws + off);        off += (size_t)T_TOK * 256 * 4;   // 16.78 MB
  float* Q = (float*)(ws + off);        off += (size_t)NQ * 256 * 4;      // 1.57 MB
  float* imp = (float*)(ws + off);      off += (size_t)T_TOK * 4;
  int* selected = (int*)(ws + off);     off += (size_t)NQ * 4;
  int* lo = (int*)(ws + off);           off += 64;
  int* hi = (int*)(ws + off);           off += 64;
  unsigned long long* topk2 = (unsigned long long*)(ws + off);
  off += (size_t)NQ * NH * 4 * KT * 8;                                    // 1.97 MB
  uint4* WkH = (uint4*)(ws + off);      off += (size_t)32 * 256 * 16;     // 128 KB
  uint4* WvH = (uint4*)(ws + off);      off += (size_t)32 * 256 * 16;     // 128 KB
  float4* WqP = (float4*)(ws + off);    off += (size_t)64 * 256 * 16;     // 256 KB
  float4* WoP = (float4*)(ws + off);    off += (size_t)64 * 256 * 16;
  float4* Wi1P = (float4*)(ws + off);   off += (size_t)64 * 128 * 16;     // 128 KB
  (void)ws_size; (void)in_sizes; (void)n_in; (void)out_size;

  wpanel_kernel<<<256, 64, 0, stream>>>(Wk, Wv, Wq, Wo, Wi1, WkH, WvH, WqP,
                                        WoP, Wi1P);
  kvimp_kernel<<<1536, 256, 0, stream>>>(X, WkH, bk, WvH, bv, Wi1P, bi1, Wi2,
                                         bi2, Kmat, V, imp);
  topselq_kernel<<<M_MSG + 1, 256, 0, stream>>>(imp, mb, bidx, X, WqP, bq,
                                                selected, lo, hi, Q);
  scores_kernel<<<M_MSG * NH * 2, 128, 0, stream>>>(Q, Kmat, lo, hi, bidx,
                                                    topk2);
  hipMemcpyAsync(out, X, (size_t)T_TOK * D_HID * sizeof(float),
                 hipMemcpyDeviceToDevice, stream);
  finish_kernel<<<NQ / 4, 256, 0, stream>>>(topk2, V, WoP, bo, selected, out,
                                            out_avg);
}

// Round 25
// 185.954 us; speedup vs baseline: 1.1280x; 1.1280x over previous
//
#include <hip/hip_runtime.h>
#include <math.h>

#define T_TOK 16384
#define M_MSG 256
#define L_TOK 64
#define KK 6
#define NQ (M_MSG * KK)   // 1536
#define D_HID 256
#define NH 4
#define HD 64
#define KT 10
#define NBATCH 8

// ---------- helpers ----------
__device__ __forceinline__ unsigned ordf(float f) {
  unsigned u = __float_as_uint(f);
  return (u & 0x80000000u) ? ~u : (u | 0x80000000u);
}
__device__ __forceinline__ float unordf(unsigned u) {
  return __uint_as_float((u & 0x80000000u) ? (u ^ 0x80000000u) : ~u);
}

typedef _Float16 h2v __attribute__((ext_vector_type(2)));
typedef _Float16 h8v __attribute__((ext_vector_type(8)));
typedef float f4v __attribute__((ext_vector_type(4)));
typedef __fp16 fp16x2 __attribute__((ext_vector_type(2)));  // cvt_pkrtz ret type
__device__ __forceinline__ h2v u2h(unsigned u) {
  return __builtin_bit_cast(h2v, u);
}
// pack two f32 -> f16x2 (RTZ; v_cvt_pkrtz_f16_f32, available all gfx9+)
__device__ __forceinline__ unsigned pkh(float a, float b) {
  fp16x2 h = __builtin_amdgcn_cvt_pkrtz(a, b);
  return __builtin_bit_cast(unsigned, h);
}
#if defined(__has_builtin) && __has_builtin(__builtin_amdgcn_fdot2)
__device__ __forceinline__ float FDOT2(h2v a, h2v b, float c) {
  return __builtin_amdgcn_fdot2(a, b, c, false);  // v_dot2_f32_f16: 2 MACs
}
#else
__device__ __forceinline__ float FDOT2(h2v a, h2v b, float c) {
  return c + (float)a.x * (float)b.x + (float)a.y * (float)b.y;
}
#endif

// ---------- 0. weight panel transpose ----------
// WqP/WoP/Wi1P: f32 k-panels (coalesced float4 per column).
// WkH/WvH: f16-packed dim-major panels WH[d8*256+c] = uint4 of dims
// d8*8..d8*8+7 of column c (= the MFMA B-fragment layout).
__global__ __launch_bounds__(64) void wpanel_kernel(
    const float* __restrict__ Wk, const float* __restrict__ Wv,
    const float* __restrict__ Wq, const float* __restrict__ Wo,
    const float* __restrict__ Wi1, uint4* __restrict__ WkH,
    uint4* __restrict__ WvH, float4* __restrict__ WqP,
    float4* __restrict__ WoP, float4* __restrict__ Wi1P) {
  int c = blockIdx.x;    // 0..255 (column)
  int t = threadIdx.x;   // 0..63
  WqP[t * 256 + c] = ((const float4*)(Wq + (size_t)c * 256))[t];
  WoP[t * 256 + c] = ((const float4*)(Wo + (size_t)c * 256))[t];
  if (c < 128) Wi1P[t * 128 + c] = ((const float4*)(Wi1 + (size_t)c * 256))[t];
  const float* Wsrc = (t < 32) ? Wk : Wv;
  uint4* dst = (t < 32) ? WkH : WvH;
  int d8 = t & 31;
  float4 a = ((const float4*)(Wsrc + (size_t)c * 256))[d8 * 2];
  float4 b = ((const float4*)(Wsrc + (size_t)c * 256))[d8 * 2 + 1];
  uint4 p;
  p.x = pkh(a.x, a.y);
  p.y = pkh(a.z, a.w);
  p.z = pkh(b.x, b.y);
  p.w = pkh(b.z, b.w);
  dst[d8 * 256 + c] = p;
}

// ---------- 1. fused KV-projection (MFMA f16) + importance MLP (f32) ----------
// KV path: X tile f16-packed in LDS; K+V computed with
// v_mfma_f32_16x16x32_f16. Wave w owns {K,V}x{cols 0-127,128-255}.
// A-frags: 8 aligned uint4 LDS reads. B-frags: panel uint4 per (kb,tile).
// C/D layout: col=lane&15, row=(lane>>4)*4+reg. V: bias + direct stores.
// K: bias -> LDS rows 16..31 -> packed f16 store (dim-major Kb[h*8+d8][t]).
// imp path untouched (f32 exact -- selection flips would be large errors).
__global__ __launch_bounds__(256) void kvimp_kernel(
    const float* __restrict__ X, const uint4* __restrict__ WkH,
    const float* __restrict__ bk, const uint4* __restrict__ WvH,
    const float* __restrict__ bv, const float4* __restrict__ Wi1P,
    const float* __restrict__ bi1, const float* __restrict__ Wi2,
    const float* __restrict__ bi2, unsigned* __restrict__ Kout,
    float* __restrict__ Vout, float* __restrict__ imp) {
  __shared__ float xs[32][260];  // rows 0..8: f16 X tile; rows 16..31: K res
  __shared__ float partial[4][16];
  int tid = threadIdx.x;
  if (blockIdx.x < 1024) {
    // ---- KV path (16 rows, MFMA) ----
    int r0 = blockIdx.x * 16;
    unsigned* xh = (unsigned*)&xs[0][0];  // [16][132] u32 (row = 528 B)
    const float4* Xv = (const float4*)(X + (size_t)r0 * 256);
#pragma unroll
    for (int i = 0; i < 2; ++i) {
      int n = i * 256 + tid;   // 0..511
      int row = n >> 5, d8 = n & 31;
      float4 a = Xv[row * 64 + d8 * 2];
      float4 b = Xv[row * 64 + d8 * 2 + 1];
      uint4 p;
      p.x = pkh(a.x, a.y);
      p.y = pkh(a.z, a.w);
      p.z = pkh(b.x, b.y);
      p.w = pkh(b.z, b.w);
      ((uint4*)(xh + row * 132))[d8] = p;
    }
    __syncthreads();
    int lane = tid & 63, w = tid >> 6;
    int mat = w >> 1;            // 0 = K, 1 = V
    int cbase = (w & 1) * 128;   // column base for this wave
    int arow = lane & 15, akg = lane >> 4;
    const uint4* P = mat ? WvH : WkH;
    // hoist A-fragments (shared across the wave's 8 col-tiles)
    uint4 a8[8];
#pragma unroll
    for (int kb = 0; kb < 8; ++kb)
      a8[kb] = ((const uint4*)xh)[arow * 33 + kb * 4 + akg];
#pragma unroll
    for (int tt = 0; tt < 8; ++tt) {
      int c0 = cbase + tt * 16;
      f4v acc = {0.f, 0.f, 0.f, 0.f};
#pragma unroll
      for (int kb = 0; kb < 8; ++kb) {
        uint4 b = P[(size_t)(kb * 4 + akg) * 256 + c0 + arow];
        acc = __builtin_amdgcn_mfma_f32_16x16x32_f16(
            __builtin_bit_cast(h8v, a8[kb]), __builtin_bit_cast(h8v, b), acc,
            0, 0, 0);
      }
      int col = c0 + arow;
      if (mat == 0) {
        float bb = bk[col];
#pragma unroll
        for (int r = 0; r < 4; ++r)
          xs[16 + akg * 4 + r][col] = acc[r] + bb;
      } else {
        float bb = bv[col];
#pragma unroll
        for (int r = 0; r < 4; ++r)
          Vout[(size_t)(r0 + akg * 4 + r) * 256 + col] = acc[r] + bb;
      }
    }
    __syncthreads();  // K results visible in rows 16..31
    uint4* Kbv = (uint4*)Kout;
#pragma unroll
    for (int i = 0; i < 2; ++i) {
      int idx = i * 256 + tid;    // 0..511
      int hd8 = idx >> 4;         // 0..31 (h*8 + d8)
      int r = idx & 15;
      const float* row = &xs[16 + r][hd8 * 8];
      uint4 p;
      p.x = pkh(row[0], row[1]);
      p.y = pkh(row[2], row[3]);
      p.z = pkh(row[4], row[5]);
      p.w = pkh(row[6], row[7]);
      Kbv[(size_t)hd8 * T_TOK + r0 + r] = p;
    }
  } else {
    // ---- imp path (32 tokens; grp g = tid>>7 owns tokens g*16..+15) ----
    int t0 = (blockIdx.x - 1024) * 32;
    const float4* Xv = (const float4*)(X + (size_t)t0 * 256);
    for (int n = tid; n < 2048; n += 256) {
      int row = n >> 6, sl = n & 63;
      ((float4*)xs[row])[sl] = Xv[row * 64 + sl];
    }
    __syncthreads();
    int j = tid & 127, grp = tid >> 7;
    float acc[16];
#pragma unroll
    for (int tt = 0; tt < 16; ++tt) acc[tt] = 0.f;
    for (int i4 = 0; i4 < 64; ++i4) {
      float4 w = Wi1P[i4 * 128 + j];
#pragma unroll
      for (int tt = 0; tt < 16; ++tt) {
        float4 x = ((const float4*)xs[grp * 16 + tt])[i4];
        acc[tt] += x.x * w.x + x.y * w.y + x.z * w.z + x.w * w.w;
      }
    }
    float b1 = bi1[j], w2 = Wi2[j];
    float p[16];
#pragma unroll
    for (int tt = 0; tt < 16; ++tt) {
      float hh = acc[tt] + b1;
      hh = hh > 0.f ? hh : 0.f;
      p[tt] = hh * w2;
    }
#pragma unroll
    for (int s = 1; s < 64; s <<= 1) {
#pragma unroll
      for (int tt = 0; tt < 16; ++tt) p[tt] += __shfl_xor(p[tt], s, 64);
    }
    int lane = tid & 63, wv_ = tid >> 6;
    if (lane == 0) {
#pragma unroll
      for (int tt = 0; tt < 16; ++tt) partial[wv_][tt] = p[tt];
    }
    __syncthreads();
    if (tid < 32) {
      int g = tid >> 4, tt = tid & 15;
      imp[t0 + g * 16 + tt] =
          partial[2 * g][tt] + partial[2 * g + 1][tt] + bi2[0];
    }
  }
}

// ---------- 2. top-6 select + Q projection (fused) + (block M_MSG) ranges ----------
__global__ __launch_bounds__(256) void topselq_kernel(
    const float* __restrict__ imp, const int* __restrict__ mb,
    const int* __restrict__ bidx, const float* __restrict__ X,
    const float4* __restrict__ WqP, const float* __restrict__ bq,
    int* __restrict__ selected, int* __restrict__ lo, int* __restrict__ hi,
    float* __restrict__ Qout) {
  int m = blockIdx.x;
  int tid = threadIdx.x;
  if (m == M_MSG) {  // fused ranges computation
    int g = tid;
    if (g < NBATCH) {
      int l = 0;
      while (l < M_MSG && bidx[l] < g) ++l;
      int h = l;
      while (h < M_MSG && bidx[h] == g) ++h;
      lo[g] = l * L_TOK;
      hi[g] = h * L_TOK;
    }
    return;
  }
  __shared__ int sel[KK];
  __shared__ float4 xs6[KK][64];  // 6 selected rows x 256 floats (full row)
  if (tid < 64) {  // wave 0: top-6 selection
    int l = tid;
    float myv = imp[m * 64 + l];
    int start = mb[2 * m];
    for (int k = 0; k < KK; ++k) {
      float rv = myv;
      int ri = l;
#pragma unroll
      for (int s = 1; s < 64; s <<= 1) {
        float ov = __shfl_xor(rv, s, 64);
        int oi = __shfl_xor(ri, s, 64);
        if (ov > rv || (ov == rv && oi < ri)) { rv = ov; ri = oi; }
      }
      if (l == 0) {
        selected[m * KK + k] = start + ri;
        sel[k] = start + ri;
      }
      if (l == ri) myv = -INFINITY;
    }
  }
  __syncthreads();
  for (int i = tid; i < KK * 64; i += 256) {  // stage full selected rows
    int r = i >> 6, d4 = i & 63;
    xs6[r][d4] = ((const float4*)X)[(size_t)sel[r] * 64 + d4];
  }
  __syncthreads();
  float acc[KK];
#pragma unroll
  for (int r = 0; r < KK; ++r) acc[r] = 0.f;
  for (int i4 = 0; i4 < 64; ++i4) {
    float4 w = WqP[i4 * 256 + tid];
#pragma unroll
    for (int r = 0; r < KK; ++r) {
      float4 x = xs6[r][i4];
      acc[r] += x.x * w.x + x.y * w.y + x.z * w.z + x.w * w.w;
    }
  }
  float bj = bq[tid];
#pragma unroll
  for (int r = 0; r < KK; ++r)
    Qout[(size_t)(m * KK + r) * 256 + tid] = (acc[r] + bj) * 0.125f;
}

// ---------- 5. scores + per-split top-10 (f16 K/Q + dot2) ----------
// block = (m, h, split): 2048 blocks, 128 threads = 2 waves.
// Wave w owns queries w*3+{0,1,2}; lane L owns key base+L of each 64-key
// chunk. K f16 packed dim-major Kb[h*8+d8][T]: 8 coalesced loads/chunk.
// Q packed f16 at stage. Inner loop = v_dot2_f32_f16. Per-lane u64 top-10
// lists + shfl extraction merge. This exact config measured 76us (r18,
// session best); pipelining (r19), 4-way split (r20), and MFMA (r24 --
// only 6/16 B-cols real -> 62.5% dead work + 4x selection slots) all
// regressed. Established wall: VMEM load-instruction rate at this
// occupancy; bytes already halved twice (bf16 r15, f16 r17).
__global__ __launch_bounds__(128) void scores_kernel(
    const float* __restrict__ Q, const unsigned* __restrict__ Kb,
    const int* __restrict__ lo_, const int* __restrict__ hi_,
    const int* __restrict__ bidx, unsigned long long* __restrict__ topk2) {
  int bid = blockIdx.x;
  // XCD swizzle: contiguous 256-block slab per XCD (bidx sorted).
  int sw = (bid & 7) * (M_MSG * NH * 2 / 8) + (bid >> 3);
  int m = sw >> 3;
  int h = (sw >> 1) & 3;
  int sp = sw & 1;
  int tid = threadIdx.x, lane = tid & 63, w = tid >> 6;
  int g = bidx[m];
  int lo = lo_[g], hi = hi_[g];
  int range = hi - lo;
  int n_all = (range + 63) >> 6;
  int n0 = (n_all + 1) >> 1;
  int nt = sp ? (n_all - n0) : n0;
  int start = lo + (sp ? n0 * 64 : 0);
  int end0 = lo + n0 * 64;
  int end = sp ? hi : (end0 < hi ? end0 : hi);

  __shared__ uint4 qh[KK][8];  // 6 queries x 64 dims f16-packed (768 B)
  const float4* Qv = (const float4*)Q;
  for (int i = tid; i < KK * 8; i += 128) {
    int qq = i >> 3, d8 = i & 7;
    float4 a = Qv[(size_t)(m * KK + qq) * 64 + h * 16 + d8 * 2];
    float4 b = Qv[(size_t)(m * KK + qq) * 64 + h * 16 + d8 * 2 + 1];
    uint4 p;
    p.x = pkh(a.x, a.y);
    p.y = pkh(a.z, a.w);
    p.z = pkh(b.x, b.y);
    p.w = pkh(b.z, b.w);
    qh[qq][d8] = p;
  }
  __syncthreads();

  unsigned long long lst[3][KT];
#pragma unroll
  for (int j = 0; j < 3; ++j)
#pragma unroll
    for (int k = 0; k < KT; ++k) lst[j][k] = 0ULL;

  const uint4* Kh = (const uint4*)Kb + (size_t)h * 8 * T_TOK;

#pragma unroll 1
  for (int kb = 0; kb < nt; ++kb) {
    int t = start + kb * 64 + lane;
    int tc = t < hi ? t : hi - 1;
    uint4 kw[8];
#pragma unroll
    for (int d8 = 0; d8 < 8; ++d8) kw[d8] = Kh[(size_t)d8 * T_TOK + tc];
    float acc[3];
    acc[0] = 0.f; acc[1] = 0.f; acc[2] = 0.f;
#pragma unroll
    for (int d8 = 0; d8 < 8; ++d8) {
      uint4 kv = kw[d8];
#pragma unroll
      for (int j = 0; j < 3; ++j) {
        uint4 qv = qh[w * 3 + j][d8];
        float a = acc[j];
        a = FDOT2(u2h(kv.x), u2h(qv.x), a);
        a = FDOT2(u2h(kv.y), u2h(qv.y), a);
        a = FDOT2(u2h(kv.z), u2h(qv.z), a);
        a = FDOT2(u2h(kv.w), u2h(qv.w), a);
        acc[j] = a;
      }
    }
    bool v0 = (t < end) && ((t >> 6) != m);
    unsigned nk = ~(unsigned)t;
#pragma unroll
    for (int j = 0; j < 3; ++j) {
      unsigned cc = v0 ? ordf(acc[j]) : 0u;
      unsigned long long key =
          cc ? (((unsigned long long)cc << 32) | nk) : 0ULL;
      if (key > lst[j][KT - 1]) {
        unsigned long long ins = key;
#pragma unroll
        for (int r = 0; r < KT; ++r) {
          unsigned long long cur = lst[j][r];
          unsigned long long mx = ins > cur ? ins : cur;
          unsigned long long mn = ins > cur ? cur : ins;
          lst[j][r] = mx;
          ins = mn;
        }
      }
    }
  }

  // ---- extraction merge across 64 lanes (3 queries interleaved for ILP) ----
  for (int k = 0; k < KT; ++k) {
    unsigned long long mx[3];
#pragma unroll
    for (int j = 0; j < 3; ++j) mx[j] = lst[j][0];
#pragma unroll
    for (int s_ = 1; s_ < 64; s_ <<= 1) {
#pragma unroll
      for (int j = 0; j < 3; ++j) {
        unsigned long long o = __shfl_xor(mx[j], s_, 64);
        if (o > mx[j]) mx[j] = o;
      }
    }
#pragma unroll
    for (int j = 0; j < 3; ++j) {
      if (mx[j] != 0ULL && lst[j][0] == mx[j]) {
#pragma unroll
        for (int r = 0; r < KT - 1; ++r) lst[j][r] = lst[j][r + 1];
        lst[j][KT - 1] = 0ULL;
      }
    }
    if (lane == 0) {
#pragma unroll
      for (int j = 0; j < 3; ++j) {
        int q = m * KK + w * 3 + j;
        topk2[((size_t)(q * NH + h) * 2 + sp) * KT + k] = mx[j];
      }
    }
  }
}

// ---------- 6. merge splits + softmax + gather V + Wo + scatter-add + avg ----------
// 4 queries/block (384 blocks): 4x the waves of the old 16/block grid,
// 1/4 the per-thread serial work; per-output arithmetic and scatter
// targets identical. Wo panel re-reads stay L2-resident.
__global__ __launch_bounds__(256) void finish_kernel(
    const unsigned long long* __restrict__ topk2, const float* __restrict__ V,
    const float4* __restrict__ WoP, const float* __restrict__ bo,
    const int* __restrict__ selected, float* __restrict__ out,
    float* __restrict__ out_avg) {
  int q0 = blockIdx.x * 4;
  int tid = threadIdx.x;
  __shared__ unsigned long long buf[16][2 * KT];  // 2.5 KB
  __shared__ float tvs[4][NH][KT];
  __shared__ int tis[4][NH][KT];
  __shared__ float wsm[4][NH * KT];
  __shared__ float att[4][256];
  // stage the 16 (q,h) pairs' split lists
  const unsigned long long* src = topk2 + (size_t)q0 * NH * 2 * KT;
  for (int i = tid; i < 16 * 2 * KT; i += 256) (&buf[0][0])[i] = src[i];
  __syncthreads();
  if (tid < 16) {
    int qq = tid >> 2, h = tid & 3;
    // two-pointer exact merge of the two sorted-desc lists + inline softmax
    int pa = 0, pb = 0;
    float e[KT];
    float m0 = 0.f, sum = 0.f;
#pragma unroll
    for (int k = 0; k < KT; ++k) {
      unsigned long long va = buf[tid][pa];
      unsigned long long vb = buf[tid][KT + pb];
      unsigned long long v;
      if (va >= vb) { v = va; ++pa; } else { v = vb; ++pb; }
      float scv;
      int t;
      if (v != 0ULL) {
        scv = unordf((unsigned)(v >> 32));
        t = (int)(~(unsigned)v);
      } else {
        scv = -1e30f;
        t = 0;
      }
      tvs[qq][h][k] = scv;
      tis[qq][h][k] = t;
      if (k == 0) m0 = scv;
      e[k] = expf(scv - m0);
      sum += e[k];
    }
    float inv = 1.f / sum;
#pragma unroll
    for (int k = 0; k < KT; ++k) wsm[qq][h * KT + k] = e[k] * inv;
  }
  __syncthreads();
  if (tid < 40) {
    int qq = tid / 10, k = tid % 10;
    out_avg[(size_t)(q0 + qq) * KT + k] =
        0.25f * (tvs[qq][0][k] + tvs[qq][1][k] + tvs[qq][2][k] + tvs[qq][3][k]);
  }
  int h = tid >> 6, d = tid & 63;
#pragma unroll 1
  for (int qq = 0; qq < 4; ++qq) {
    float a = 0.f;
#pragma unroll
    for (int k = 0; k < KT; ++k) {
      int t = tis[qq][h][k];
      a += wsm[qq][h * KT + k] * V[(size_t)t * 256 + h * 64 + d];
    }
    att[qq][tid] = a;
  }
  __syncthreads();
  float acc[4];
#pragma unroll
  for (int tt = 0; tt < 4; ++tt) acc[tt] = 0.f;
  for (int i4 = 0; i4 < 64; ++i4) {
    float4 wv = WoP[i4 * 256 + tid];  // coalesced panel load (L2-resident)
#pragma unroll
    for (int tt = 0; tt < 4; ++tt) {
      float4 x = ((const float4*)att[tt])[i4];
      acc[tt] += x.x * wv.x + x.y * wv.y + x.z * wv.z + x.w * wv.w;
    }
  }
  float bj = bo[tid];
#pragma unroll 1
  for (int tt = 0; tt < 4; ++tt) {
    int s = selected[q0 + tt];
    out[(size_t)s * 256 + tid] += acc[tt] + bj;
  }
}

// ---------- launch ----------
extern "C" void kernel_launch(void* const* d_in, const int* in_sizes, int n_in,
                              void* d_out, int out_size, void* d_ws, size_t ws_size,
                              hipStream_t stream) {
  const float* X   = (const float*)d_in[0];
  const int*   mb  = (const int*)d_in[1];
  const int*   bidx= (const int*)d_in[2];
  const float* Wq  = (const float*)d_in[3];
  const float* bq  = (const float*)d_in[4];
  const float* Wk  = (const float*)d_in[5];
  const float* bk  = (const float*)d_in[6];
  const float* Wv  = (const float*)d_in[7];
  const float* bv  = (const float*)d_in[8];
  const float* Wi1 = (const float*)d_in[9];
  const float* bi1 = (const float*)d_in[10];
  const float* Wi2 = (const float*)d_in[11];
  const float* bi2 = (const float*)d_in[12];
  const float* Wo  = (const float*)d_in[13];
  const float* bo  = (const float*)d_in[14];

  float* out = (float*)d_out;
  float* out_avg = out + (size_t)T_TOK * D_HID;

  // K (f16 packed, 8 MB) is staged in d_out's "updated" region
  // (dead until final memcpy+scatter).
  unsigned* Kmat = (unsigned*)out;

  char* ws = (char*)d_ws;
  size_t off = 0;
  float* V = (float*)(ws + off);        off += (size_t)T_TOK * 256 * 4;   // 16.78 MB
  float* Q = (float*)(ws + off);        off += (size_t)NQ * 256 * 4;      // 1.57 MB
  float* imp = (float*)(ws + off);      off += (size_t)T_TOK * 4;
  int* selected = (int*)(ws + off);     off += (size_t)NQ * 4;
  int* lo = (int*)(ws + off);           off += 64;
  int* hi = (int*)(ws + off);           off += 64;
  unsigned long long* topk2 = (unsigned long long*)(ws + off);
  off += (size_t)NQ * NH * 2 * KT * 8;                                    // 0.98 MB
  uint4* WkH = (uint4*)(ws + off);      off += (size_t)32 * 256 * 16;     // 128 KB
  uint4* WvH = (uint4*)(ws + off);      off += (size_t)32 * 256 * 16;     // 128 KB
  float4* WqP = (float4*)(ws + off);    off += (size_t)64 * 256 * 16;     // 256 KB
  float4* WoP = (float4*)(ws + off);    off += (size_t)64 * 256 * 16;
  float4* Wi1P = (float4*)(ws + off);   off += (size_t)64 * 128 * 16;     // 128 KB
  (void)ws_size; (void)in_sizes; (void)n_in; (void)out_size;

  wpanel_kernel<<<256, 64, 0, stream>>>(Wk, Wv, Wq, Wo, Wi1, WkH, WvH, WqP,
                                        WoP, Wi1P);
  kvimp_kernel<<<1536, 256, 0, stream>>>(X, WkH, bk, WvH, bv, Wi1P, bi1, Wi2,
                                         bi2, Kmat, V, imp);
  topselq_kernel<<<M_MSG + 1, 256, 0, stream>>>(imp, mb, bidx, X, WqP, bq,
                                                selected, lo, hi, Q);
  scores_kernel<<<M_MSG * NH * 2, 128, 0, stream>>>(Q, Kmat, lo, hi, bidx,
                                                    topk2);
  hipMemcpyAsync(out, X, (size_t)T_TOK * D_HID * sizeof(float),
                 hipMemcpyDeviceToDevice, stream);
  finish_kernel<<<NQ / 4, 256, 0, stream>>>(topk2, V, WoP, bo, selected, out,
                                            out_avg);
}